// Round 6
// baseline (190.792 us; speedup 1.0000x reference)
//
#include <hip/hip_runtime.h>

// Shapes: B=2, F=T=2048, HIDDEN=1024, HEADS=16, DEPTH=64
#define LOG2E 1.44269504f

typedef __attribute__((ext_vector_type(8))) short short8v;   // 8 bf16
typedef __attribute__((ext_vector_type(4))) float f32x4;
typedef __attribute__((ext_vector_type(16))) float f32x16;
typedef unsigned int u32;
typedef __attribute__((ext_vector_type(4))) u32 u32x4;
typedef __attribute__((address_space(1))) const u32* gp_t;
typedef __attribute__((address_space(3))) u32* lp_t;

#define MFMA(a, b, c) __builtin_amdgcn_mfma_f32_16x16x32_bf16((a), (b), (c), 0, 0, 0)
#define MFMA32(a, b, c) __builtin_amdgcn_mfma_f32_32x32x16_bf16((a), (b), (c), 0, 0, 0)

__device__ __forceinline__ unsigned short f2bf(float f) {  // RNE fp32->bf16
  unsigned int u = __float_as_uint(f);
  u = (u + 0x7fffu + ((u >> 16) & 1u)) >> 16;
  return (unsigned short)u;
}
__device__ __forceinline__ u32 cvtpk(float lo, float hi) {  // HW RNE pack (T12)
  u32 r;
  asm("v_cvt_pk_bf16_f32 %0, %1, %2" : "=v"(r) : "v"(lo), "v"(hi));
  return r;
}
// v_permlane32_swap_b32: a.hi32lanes <-> b.lo32lanes  (T12)
__device__ __forceinline__ void pl32swap(u32& a, u32& b) {
  asm("v_permlane32_swap_b32 %0, %1" : "+v"(a), "+v"(b));
}
__device__ __forceinline__ float max3f(float a, float b, float c) {
  return fmaxf(fmaxf(a, b), c);  // fuses to v_max3_f32
}

// ---------------- fp32 -> bf16 convert (x4 vectorized) ----------------
__global__ void k_cvt(const float* __restrict__ in, unsigned short* __restrict__ out,
                      int n4, float scale) {
  int stride = gridDim.x * blockDim.x;
  for (int i = blockIdx.x * blockDim.x + threadIdx.x; i < n4; i += stride) {
    float4 v = reinterpret_cast<const float4*>(in)[i];
    ushort4 o;
    o.x = f2bf(v.x * scale); o.y = f2bf(v.y * scale);
    o.z = f2bf(v.z * scale); o.w = f2bf(v.w * scale);
    reinterpret_cast<ushort4*>(out)[i] = o;
  }
}

// ------------- transpose+convert 1024x1024 weight: out[j][i] = in[i][j]*scale -------------
__global__ void k_cvt_t(const float* __restrict__ in, unsigned short* __restrict__ out,
                        float scale) {
  __shared__ float tile[32][33];
  int bx = blockIdx.x * 32, by = blockIdx.y * 32;
  int tx = threadIdx.x, ty = threadIdx.y;  // block (32,8)
  for (int r = ty; r < 32; r += 8)
    tile[r][tx] = in[(size_t)(by + r) * 1024 + bx + tx];
  __syncthreads();
  for (int r = ty; r < 32; r += 8)
    out[(size_t)(bx + r) * 1024 + by + tx] = f2bf(tile[tx][r] * scale);
}

// ---- bias permute to f32 32x32-MFMA C-fragment layout, *LOG2E ----
// attn reads: b[sq] at float idx ((fb2*32+ci)*64 + lane)*32 + sq, sq = sub*16 + q,
// value = bias[fb2*32 + (lane&31)][ci*64 + sub*32 + (q&3) + 8*(q>>2) + 4*(lane>>5)]
__global__ void k_bias_perm(const float* __restrict__ in, float* __restrict__ out) {
  int bid = blockIdx.x;  // fb2*32 + ci, grid 2048
  int fb2 = bid >> 5, ci = bid & 31;
  int t = threadIdx.x;
  int l = t & 63, part = t >> 6;  // part 0..3 -> sq = part*8 + j
  int l31 = l & 31, hi = l >> 5;
  int sub = part >> 1;
  int qb = (part & 1) * 8;
  const float* ib = in + (size_t)(fb2 * 32 + l31) * 2048 + ci * 64 + sub * 32 + 8 * (qb >> 2) + 4 * hi;
  float4 v0 = *reinterpret_cast<const float4*>(ib);
  float4 v1 = *reinterpret_cast<const float4*>(ib + 8);
  float* ob = out + ((size_t)bid * 64 + l) * 32 + part * 8;
  v0.x *= LOG2E; v0.y *= LOG2E; v0.z *= LOG2E; v0.w *= LOG2E;
  v1.x *= LOG2E; v1.y *= LOG2E; v1.z *= LOG2E; v1.w *= LOG2E;
  *reinterpret_cast<float4*>(ob) = v0;
  *reinterpret_cast<float4*>(ob + 4) = v1;
}

// ------------- bf16 GEMM: BM=BN=BK=64, 4 waves (2x2), dbuf, gload_lds, XOR swizzle ------
// TC=1: compute C^T via MFMA(b,a) -> per-lane reg quad lies on the W-col (contiguous out dim)
// MODE 0: bf16 -> [bh][s][64] (Q,K; TC=1)   MODE 1: bf16 -> [bh][h][2048] (V^T; TC=0)
// MODE 2: f32 row-major [4096][1024] (TC=1)
template <int TC, int MODE>
__global__ __launch_bounds__(256, 4)
void k_gemm(const unsigned short* __restrict__ A, const unsigned short* __restrict__ BT,
            void* __restrict__ dstv) {
  __shared__ __align__(16) unsigned short Al[2][4096];
  __shared__ __align__(16) unsigned short Bl[2][4096];
  const int tid = threadIdx.x;
  const int lane = tid & 63, wid = tid >> 6;
  const int g = lane >> 4, l15 = lane & 15, l7 = l15 & 7;
  const int wm = wid >> 1, wn = wid & 1;
  const int rowbase = blockIdx.y * 64, colbase = blockIdx.x * 64;
  const int xgl = (g ^ l7) << 4;

  const int jr = tid >> 3;
  const int sc = ((tid & 7) ^ (jr & 7)) << 3;
  const unsigned short* As0 = A + (size_t)(rowbase + jr) * 1024 + sc;
  const unsigned short* As1 = A + (size_t)(rowbase + jr + 32) * 1024 + sc;
  const unsigned short* Bs0 = BT + (size_t)(colbase + jr) * 1024 + sc;
  const unsigned short* Bs1 = BT + (size_t)(colbase + jr + 32) * 1024 + sc;

  const f32x4 zf = {0.f, 0.f, 0.f, 0.f};
  f32x4 acc[2][2];
  acc[0][0] = zf; acc[0][1] = zf; acc[1][0] = zf; acc[1][1] = zf;

  auto stage = [&](int buf, int k0) {
    char* Ad = (char*)&Al[buf][0];
    char* Bd = (char*)&Bl[buf][0];
    __builtin_amdgcn_global_load_lds((gp_t)(As0 + k0), (lp_t)(Ad + tid * 16), 16, 0, 0);
    __builtin_amdgcn_global_load_lds((gp_t)(As1 + k0), (lp_t)(Ad + 4096 + tid * 16), 16, 0, 0);
    __builtin_amdgcn_global_load_lds((gp_t)(Bs0 + k0), (lp_t)(Bd + tid * 16), 16, 0, 0);
    __builtin_amdgcn_global_load_lds((gp_t)(Bs1 + k0), (lp_t)(Bd + 4096 + tid * 16), 16, 0, 0);
  };
  auto compute = [&](int buf) {
    const char* Ac = (const char*)&Al[buf][0];
    const char* Bc = (const char*)&Bl[buf][0];
    __builtin_amdgcn_s_setprio(1);
#pragma unroll
    for (int kk = 0; kk < 2; ++kk) {
      short8v af[2], bfr[2];
#pragma unroll
      for (int mf = 0; mf < 2; ++mf)
        af[mf] = *reinterpret_cast<const short8v*>(
            Ac + ((wm * 32 + mf * 16 + l15) << 7) + (xgl ^ (kk << 6)));
#pragma unroll
      for (int nf = 0; nf < 2; ++nf)
        bfr[nf] = *reinterpret_cast<const short8v*>(
            Bc + ((wn * 32 + nf * 16 + l15) << 7) + (xgl ^ (kk << 6)));
#pragma unroll
      for (int mf = 0; mf < 2; ++mf)
#pragma unroll
        for (int nf = 0; nf < 2; ++nf)
          acc[mf][nf] = TC ? MFMA(bfr[nf], af[mf], acc[mf][nf])
                           : MFMA(af[mf], bfr[nf], acc[mf][nf]);
    }
    __builtin_amdgcn_s_setprio(0);
  };

  stage(0, 0);
  __syncthreads();
#pragma unroll 1
  for (int s = 0; s < 16; ++s) {
    if (s < 15) stage((s + 1) & 1, (s + 1) * 64);
    compute(s & 1);
    __syncthreads();
  }

#pragma unroll
  for (int mf = 0; mf < 2; ++mf)
#pragma unroll
    for (int nf = 0; nf < 2; ++nf) {
      f32x4 v = acc[mf][nf];
      if (MODE == 2) {  // TC=1: lane row s, reg quad = cols c..c+3
        int s = rowbase + wm * 32 + mf * 16 + l15;
        int c = colbase + wn * 32 + nf * 16 + g * 4;
        *reinterpret_cast<f32x4*>((float*)dstv + (size_t)s * 1024 + c) = v;
      } else if (MODE == 0) {  // TC=1: bf16 [bh][s][64], reg quad on h
        int s = rowbase + wm * 32 + mf * 16 + l15;
        int c = colbase + wn * 32 + nf * 16 + g * 4;
        int b = s >> 11, s2 = s & 2047, hd = c >> 6, h = c & 63;
        uint2 w; w.x = cvtpk(v[0], v[1]); w.y = cvtpk(v[2], v[3]);
        *reinterpret_cast<uint2*>((unsigned short*)dstv +
            ((size_t)(b * 16 + hd) * 2048 + s2) * 64 + h) = w;
      } else {  // MODE 1, TC=0: V^T [bh][h][2048], reg quad on s
        int s = rowbase + wm * 32 + mf * 16 + g * 4;
        int c = colbase + wn * 32 + nf * 16 + l15;
        int b = s >> 11, s2 = s & 2047, hd = c >> 6, h = c & 63;
        uint2 w; w.x = cvtpk(v[0], v[1]); w.y = cvtpk(v[2], v[3]);
        *reinterpret_cast<uint2*>((unsigned short*)dstv +
            ((size_t)(b * 16 + hd) * 64 + h) * 2048 + s2) = w;
      }
    }
}

// ---------------- flash attention, 32x32 MFMA, lane-local softmax ----------------
// block = 128 threads (2 waves x 32 f-rows); grid = 32 ftiles x 32 bh = 1024 (4/CU).
// S^T = MFMA32(K, Q) + bias(C-init): lane&31 = f-row; lane holds 32 of 64 t-values.
// P->bf16 via cvtpk + permlane32_swap (in-register, no LDS). O^T = MFMA32(V^T, P).
__global__ __launch_bounds__(128, 2)
void k_attn(const unsigned short* __restrict__ qw,    // [B*N][F][64] (* scale * log2e)
            const unsigned short* __restrict__ kw,    // [B*N][T][64]
            const unsigned short* __restrict__ vtw,   // [B*N][64][T]
            const float* __restrict__ biaspf,         // f32 32x32 C-frag layout (* log2e)
            unsigned short* __restrict__ attnb) {     // [B][F][N*64] bf16
  __shared__ __align__(16) unsigned short Kl[2][4096];
  __shared__ __align__(16) unsigned short Vl[2][4096];

  const int tid = threadIdx.x;              // 0..127
  const int lane = tid & 63, wid = tid >> 6;
  const int l31 = lane & 31, hi = lane >> 5;

  const int bid = blockIdx.x;  // ft-major: 32 consecutive blocks share a bias slab
  const int ft = bid >> 5, bn = bid & 31;
  const int b = bn >> 4, n = bn & 15;

  const size_t hoff = (size_t)bn * (2048 * 64);
  const unsigned short* qp = qw + hoff;
  const unsigned short* kp = kw + hoff;
  const unsigned short* vp = vtw + hoff;

  const int f0 = ft * 64 + wid * 32;
  const int fb2 = ft * 2 + wid;

  // staging: 128 threads x 4 passes for K (64x64 bf16), 4 for V; pre-swizzled source
  const int r0 = tid >> 3;  // 0..15
  const int sc = ((tid & 7) ^ (r0 & 7)) << 3;

  auto stage = [&](int buf, int ci) {
    char* Kd = (char*)&Kl[buf][0];
    char* Vd = (char*)&Vl[buf][0];
    const unsigned short* ks = kp + (size_t)ci * 4096;
    const unsigned short* vs = vp + ci * 64;
#pragma unroll
    for (int p = 0; p < 4; ++p)
      __builtin_amdgcn_global_load_lds((gp_t)(ks + (p * 16 + r0) * 64 + sc),
                                       (lp_t)(Kd + (p * 128 + tid) * 16), 16, 0, 0);
#pragma unroll
    for (int p = 0; p < 4; ++p)
      __builtin_amdgcn_global_load_lds((gp_t)(vs + (size_t)(p * 16 + r0) * 2048 + sc),
                                       (lp_t)(Vd + (p * 128 + tid) * 16), 16, 0, 0);
  };

  // Q as B-fragment: col = f = f0+l31, k = kk*16 + hi*8 + j
  short8v aq[4];
#pragma unroll
  for (int kk = 0; kk < 4; ++kk)
    aq[kk] = *reinterpret_cast<const short8v*>(&qp[(size_t)(f0 + l31) * 64 + kk * 16 + hi * 8]);

  const f32x16* bias16 = (const f32x16*)(biaspf + ((size_t)fb2 * 32 * 64 + lane) * 32);
  auto bload = [&](int ci, f32x16& b0, f32x16& b1) {
    b0 = bias16[(size_t)ci * 128];
    b1 = bias16[(size_t)ci * 128 + 1];
  };

  f32x16 o0, o1;
#pragma unroll
  for (int q = 0; q < 16; ++q) { o0[q] = 0.f; o1[q] = 0.f; }
  float ms = -1e30f, ls = 0.f;

  const int rb = l31 * 128;
  const int rx = (l31 & 7) << 4;

  auto compute = [&](int buf, const f32x16& bc0, const f32x16& bc1) {
    const char* Kc = (const char*)&Kl[buf][0];
    const char* Vc = (const char*)&Vl[buf][0];
    f32x16 st0 = bc0, st1 = bc1;
    __builtin_amdgcn_s_setprio(1);
#pragma unroll
    for (int kk = 0; kk < 4; ++kk) {
      short8v kf = *reinterpret_cast<const short8v*>(Kc + ((rb + kk * 32 + hi * 16) ^ rx));
      st0 = MFMA32(kf, aq[kk], st0);
    }
#pragma unroll
    for (int kk = 0; kk < 4; ++kk) {
      short8v kf = *reinterpret_cast<const short8v*>(Kc + 4096 + ((rb + kk * 32 + hi * 16) ^ rx));
      st1 = MFMA32(kf, aq[kk], st1);
    }
    __builtin_amdgcn_s_setprio(0);

    // in-lane max over 32 values (max3 tree), then pair-reduce across hi halves
    float m0 = max3f(st0[0], st0[1], st0[2]);
    float m1 = max3f(st0[3], st0[4], st0[5]);
    float m2 = max3f(st0[6], st0[7], st0[8]);
    float m3 = max3f(st0[9], st0[10], st0[11]);
    float m4 = max3f(st0[12], st0[13], st0[14]);
    float m5 = max3f(st0[15], st1[0], st1[1]);
    float m6 = max3f(st1[2], st1[3], st1[4]);
    float m7 = max3f(st1[5], st1[6], st1[7]);
    float m8 = max3f(st1[8], st1[9], st1[10]);
    float m9 = max3f(st1[11], st1[12], st1[13]);
    float ma = fmaxf(st1[14], st1[15]);
    float tm = max3f(max3f(m0, m1, m2), max3f(m3, m4, m5), max3f(m6, m7, m8));
    tm = max3f(tm, m9, ma);
    tm = fmaxf(tm, __shfl_xor(tm, 32));

    if (__any(tm > ms + 8.0f)) {  // defer-max (T13), exp2 domain
      float mn = fmaxf(ms, tm);
      float sca = __builtin_amdgcn_exp2f(ms - mn);
      ms = mn; ls *= sca;
#pragma unroll
      for (int q = 0; q < 16; ++q) { o0[q] *= sca; o1[q] *= sca; }
    }

    float p[32];
    float rs = 0.f;
#pragma unroll
    for (int q = 0; q < 16; ++q) {
      p[q] = __builtin_amdgcn_exp2f(st0[q] - ms);
      p[16 + q] = __builtin_amdgcn_exp2f(st1[q] - ms);
      rs += p[q] + p[16 + q];
    }
    rs += __shfl_xor(rs, 32);
    ls += rs;

    // pack P into PV B-fragments: 16 cvtpk + 8 permlane32_swap (T12)
    short8v pb[4];
#pragma unroll
    for (int kk = 0; kk < 4; ++kk) {
      const int qb = (kk >> 1) * 16 + (kk & 1) * 8;
      u32 a0 = cvtpk(p[qb + 0], p[qb + 1]);
      u32 b0 = cvtpk(p[qb + 4], p[qb + 5]);
      pl32swap(a0, b0);  // a0 -> word0 (j0,1), b0 -> word2 (j4,5)
      u32 a1 = cvtpk(p[qb + 2], p[qb + 3]);
      u32 b1 = cvtpk(p[qb + 6], p[qb + 7]);
      pl32swap(a1, b1);  // a1 -> word1 (j2,3), b1 -> word3 (j6,7)
      u32x4 w; w.x = a0; w.y = a1; w.z = b0; w.w = b1;
      pb[kk] = *reinterpret_cast<short8v*>(&w);
    }

    // O^T += V^T x P : A = V^T (row h, k=t), B = P (col f, k=t)
    __builtin_amdgcn_s_setprio(1);
#pragma unroll
    for (int kk = 0; kk < 4; ++kk) {
      short8v vf = *reinterpret_cast<const short8v*>(Vc + ((rb + kk * 32 + hi * 16) ^ rx));
      o0 = MFMA32(vf, pb[kk], o0);
    }
#pragma unroll
    for (int kk = 0; kk < 4; ++kk) {
      short8v vf = *reinterpret_cast<const short8v*>(Vc + 4096 + ((rb + kk * 32 + hi * 16) ^ rx));
      o1 = MFMA32(vf, pb[kk], o1);
    }
    __builtin_amdgcn_s_setprio(0);
  };

  f32x16 bA0, bA1, bB0, bB1;
  stage(0, 0);
  bload(0, bA0, bA1);
  __syncthreads();
#pragma unroll 1
  for (int ci = 0; ci < 32; ci += 2) {
    stage(1, (ci + 1) & 31);
    bload((ci + 1) & 31, bB0, bB1);
    compute(0, bA0, bA1);
    __syncthreads();
    stage(0, (ci + 2) & 31);
    bload((ci + 2) & 31, bA0, bA1);
    compute(1, bB0, bB1);
    __syncthreads();
  }

  // epilogue: O^T col f = l31 (lane-local), rows h = (q&3)+8*(q>>2)+4hi (+32 for o1)
  float inv = 1.f / ls;
  unsigned short* ob = attnb + ((size_t)b * 2048 + f0 + l31) * 1024 + n * 64;
#pragma unroll
  for (int j = 0; j < 4; ++j) {  // q quad -> h = 8j + 4hi + 0..3
    uint2 w;
    w.x = cvtpk(o0[4 * j + 0] * inv, o0[4 * j + 1] * inv);
    w.y = cvtpk(o0[4 * j + 2] * inv, o0[4 * j + 3] * inv);
    *reinterpret_cast<uint2*>(ob + 8 * j + 4 * hi) = w;
    uint2 w2;
    w2.x = cvtpk(o1[4 * j + 0] * inv, o1[4 * j + 1] * inv);
    w2.y = cvtpk(o1[4 * j + 2] * inv, o1[4 * j + 3] * inv);
    *reinterpret_cast<uint2*>(ob + 32 + 8 * j + 4 * hi) = w2;
  }
}

extern "C" void kernel_launch(void* const* d_in, const int* in_sizes, int n_in,
                              void* d_out, int out_size, void* d_ws, size_t ws_size,
                              hipStream_t stream) {
  const float* query  = (const float*)d_in[0];
  const float* source = (const float*)d_in[1];
  const float* bias   = (const float*)d_in[2];
  const float* wq     = (const float*)d_in[3];
  const float* wk     = (const float*)d_in[4];
  const float* wv     = (const float*)d_in[5];
  const float* wo     = (const float*)d_in[6];

  char* ws = (char*)d_ws;
  unsigned short* qin_b  = (unsigned short*)(ws + 0);         // [4096][1024] bf16
  unsigned short* src_b  = (unsigned short*)(ws + 8388608);   // [4096][1024]
  float*          bias_f = (float*)(ws + 0);                  // f32 16MB, ALIASES qin/src
                                                              // (written after proj GEMMs)
  unsigned short* wqT    = (unsigned short*)(ws + 16777216);  // [1024][1024] (*0.125*log2e)
  unsigned short* wkT    = (unsigned short*)(ws + 18874368);
  unsigned short* wvT    = (unsigned short*)(ws + 20971520);
  unsigned short* woT    = (unsigned short*)(ws + 23068672);
  unsigned short* q_ws   = (unsigned short*)(ws + 25165824);  // [32][2048][64]
  unsigned short* k_ws   = (unsigned short*)(ws + 33554432);  // [32][2048][64]
  unsigned short* vT_ws  = (unsigned short*)(ws + 41943040);  // [32][64][2048]
  unsigned short* attn_b = (unsigned short*)(ws + 50331648);  // [4096][1024]

  k_cvt<<<2048, 256, 0, stream>>>(query,  qin_b, 1048576, 1.0f);
  k_cvt<<<2048, 256, 0, stream>>>(source, src_b, 1048576, 1.0f);
  dim3 tb(32, 8);
  k_cvt_t<<<dim3(32, 32), tb, 0, stream>>>(wq, wqT, 0.125f * LOG2E);
  k_cvt_t<<<dim3(32, 32), tb, 0, stream>>>(wk, wkT, 1.0f);
  k_cvt_t<<<dim3(32, 32), tb, 0, stream>>>(wv, wvT, 1.0f);
  k_cvt_t<<<dim3(32, 32), tb, 0, stream>>>(wo, woT, 1.0f);

  k_gemm<1, 0><<<dim3(16, 64), 256, 0, stream>>>(qin_b, wqT, q_ws);
  k_gemm<1, 0><<<dim3(16, 64), 256, 0, stream>>>(src_b, wkT, k_ws);
  k_gemm<0, 1><<<dim3(16, 64), 256, 0, stream>>>(src_b, wvT, vT_ws);
  k_bias_perm<<<2048, 256, 0, stream>>>(bias, bias_f);  // reuses [0,16MB) after GEMMs
  k_attn<<<1024, 128, 0, stream>>>(q_ws, k_ws, vT_ws, bias_f, attn_b);
  k_gemm<1, 2><<<dim3(16, 64), 256, 0, stream>>>(attn_b, woT, d_out);
}